// Round 2
// baseline (500.736 us; speedup 1.0000x reference)
//
#include <hip/hip_runtime.h>

#define HH 64
#define TT 512
#define BB 16

typedef __attribute__((ext_vector_type(8))) short short8;
typedef __attribute__((ext_vector_type(4))) float f32x4;

static __device__ __forceinline__ unsigned short f2bf(float f) {
  unsigned u = __float_as_uint(f);
  u += 0x7fffu + ((u >> 16) & 1u);   // round-to-nearest-even
  return (unsigned short)(u >> 16);
}

static __device__ __forceinline__ float sigm(float x) {
  float e = __builtin_amdgcn_exp2f(-1.442695041f * x);
  return __builtin_amdgcn_rcpf(1.0f + e);
}
static __device__ __forceinline__ float tanh_fast(float x) {
  float e = __builtin_amdgcn_exp2f(2.885390082f * x);
  return 1.0f - 2.0f * __builtin_amdgcn_rcpf(1.0f + e);
}

static __device__ __forceinline__ short8 pack8(const float* __restrict__ p) {
  const float4* p4 = (const float4*)p;
  float4 a = p4[0], b = p4[1];
  short8 r;
  r[0] = (short)f2bf(a.x); r[1] = (short)f2bf(a.y);
  r[2] = (short)f2bf(a.z); r[3] = (short)f2bf(a.w);
  r[4] = (short)f2bf(b.x); r[5] = (short)f2bf(b.y);
  r[6] = (short)f2bf(b.z); r[7] = (short)f2bf(b.w);
  return r;
}

// A-fragment read: lane needs h[row=m][k0 .. k0+7], k0 = kt*32 + q*8, bf16.
// Row stride 128B; 16B blocks XOR-swizzled by (row&7)<<4 (2-way/bank = free).
static __device__ __forceinline__ short8 ldfrag(const unsigned short* buf, int m, int q, int kt) {
  const int off = (kt * 64 + q * 16) ^ ((m & 7) << 4);
  return *(const short8*)((const char*)buf + m * 128 + off);
}

__global__ __launch_bounds__(1024)
void lstm2_fused(const float* __restrict__ x,
                 const float* __restrict__ Wih0, const float* __restrict__ Whh0,
                 const float* __restrict__ bih0, const float* __restrict__ bhh0,
                 const float* __restrict__ Wih1, const float* __restrict__ Whh1,
                 const float* __restrict__ bih1, const float* __restrict__ bhh1,
                 const float* __restrict__ Wfc,  const float* __restrict__ bfc,
                 float* __restrict__ out)
{
  __shared__ float xs[TT * BB];                               // 32 KB, xs[t][row]
  __shared__ __align__(16) unsigned short h0buf[2][BB * HH];  // dbuf bf16, swizzled
  __shared__ __align__(16) unsigned short h1buf[2][BB * HH];
  __shared__ float h1f[BB * HH];                              // fp32 final h1

  const int tid  = threadIdx.x;
  const int wave = tid >> 6;
  const int lane = tid & 63;
  const int grp  = wave >> 3;      // 0: layer0 (8 waves), 1: layer1 (8 waves)
  const int sub  = wave & 7;
  const int w    = sub >> 1;       // column-block 0..3
  const int jh   = sub & 1;        // row-half: handles j in {2*jh, 2*jh+1}
  const int m    = lane & 15;
  const int q    = lane >> 4;
  const int b0   = blockIdx.x * BB;

  // ---- stage x transposed: xs[t][r] = x[b0+r][t] ----
  if (tid < TT) {
    const int t = tid;
    #pragma unroll
    for (int r = 0; r < BB; ++r)
      xs[t * BB + r] = x[(size_t)(b0 + r) * TT + t];
  }
  // zero h state (bf16 zero == 0x0000); each buffer is 1024 ushorts
  h0buf[0][tid] = 0; h0buf[1][tid] = 0;
  h1buf[0][tid] = 0; h1buf[1][tid] = 0;

  // ---- pack weight B-fragments into registers (held across the whole loop) ----
  // wave (w) owns gate n-tiles {4n+w}: n=0->i,1->f,2->g,3->o, cols 16w..16w+15.
  // B-frag: lane holds Wmat[col=16*tile+m][k0+j], j=0..7, k0 = kt*32 + q*8.
  short8 wf[16];
  float bsum[4], wx[4];
  #pragma unroll
  for (int n = 0; n < 4; ++n) {
    const int colg = 16 * (4 * n + w) + m;
    if (grp == 0) {
      bsum[n] = bih0[colg] + bhh0[colg];
      wx[n]   = Wih0[colg];
      #pragma unroll
      for (int kt = 0; kt < 2; ++kt)
        wf[n * 2 + kt] = pack8(Whh0 + colg * HH + kt * 32 + q * 8);
    } else {
      bsum[n] = bih1[colg] + bhh1[colg];
      wx[n]   = 0.f;
      #pragma unroll
      for (int kt = 0; kt < 4; ++kt) {   // kt 0,1: Wih1 (h0 input); kt 2,3: Whh1
        const float* Wsrc = (kt < 2) ? Wih1 : Whh1;
        wf[n * 4 + kt] = pack8(Wsrc + colg * HH + (kt & 1) * 32 + q * 8);
      }
    }
  }

  __syncthreads();   // x staged + h zeroed

  float cst[2] = {0.f, 0.f};
  const int colw  = 16 * w + m;    // my h column within [0,64)
  const int jbase = 2 * jh;

  // iteration t: group A computes L0 step t; group B computes L1 step t-1.
  // h0(t) lives in h0buf[t&1]; h1(t) lives in h1buf[t&1]. ONE barrier/step.
  for (int t = 0; t <= TT; ++t) {
    const int p = t & 1;
    const unsigned short* h0rd = h0buf[p ^ 1];   // h0(t-1)
    const unsigned short* h1rd = h1buf[p];       // h1(t-2)
    unsigned short* h0wr = h0buf[p];             // h0(t)
    unsigned short* h1wr = h1buf[p ^ 1];         // h1(t-1)
    const bool actA = (grp == 0) && (t < TT);
    const bool actB = (grp == 1) && (t >= 1);

    if (actA) {
      short8 af0 = ldfrag(h0rd, m, q, 0);
      short8 af1 = ldfrag(h0rd, m, q, 1);
      f32x4 acc[4];
      #pragma unroll
      for (int n = 0; n < 4; ++n) {
        acc[n][0] = bsum[n]; acc[n][1] = bsum[n]; acc[n][2] = bsum[n]; acc[n][3] = bsum[n];
      }
      #pragma unroll
      for (int n = 0; n < 4; ++n) {
        acc[n] = __builtin_amdgcn_mfma_f32_16x16x32_bf16(af0, wf[n*2+0], acc[n], 0, 0, 0);
        acc[n] = __builtin_amdgcn_mfma_f32_16x16x32_bf16(af1, wf[n*2+1], acc[n], 0, 0, 0);
      }
      #pragma unroll
      for (int jj = 0; jj < 2; ++jj) {
        // uniform-jh select with constant vector indices (no scratch)
        float pi = jh ? acc[0][2 + jj] : acc[0][jj];
        float pf = jh ? acc[1][2 + jj] : acc[1][jj];
        float pg = jh ? acc[2][2 + jj] : acc[2][jj];
        float po = jh ? acc[3][2 + jj] : acc[3][jj];
        const float xv = xs[t * BB + q * 4 + jbase + jj];
        pi = fmaf(xv, wx[0], pi);
        pf = fmaf(xv, wx[1], pf);
        pg = fmaf(xv, wx[2], pg);
        po = fmaf(xv, wx[3], po);
        float iv = sigm(pi);
        float fv = sigm(pf);
        float gv = tanh_fast(pg);
        float ov = sigm(po);
        float c  = fmaf(fv, cst[jj], iv * gv);
        cst[jj] = c;
        float h  = ov * tanh_fast(c);
        const int row = q * 4 + jbase + jj;
        const int off = (2 * colw) ^ ((row & 7) << 4);
        *(unsigned short*)((char*)h0wr + row * 128 + off) = f2bf(h);
      }
    } else if (actB) {
      short8 af0 = ldfrag(h0rd, m, q, 0);
      short8 af1 = ldfrag(h0rd, m, q, 1);
      short8 af2 = ldfrag(h1rd, m, q, 0);
      short8 af3 = ldfrag(h1rd, m, q, 1);
      f32x4 acc[4];
      #pragma unroll
      for (int n = 0; n < 4; ++n) {
        acc[n][0] = bsum[n]; acc[n][1] = bsum[n]; acc[n][2] = bsum[n]; acc[n][3] = bsum[n];
      }
      #pragma unroll
      for (int n = 0; n < 4; ++n) {
        acc[n] = __builtin_amdgcn_mfma_f32_16x16x32_bf16(af0, wf[n*4+0], acc[n], 0, 0, 0);
        acc[n] = __builtin_amdgcn_mfma_f32_16x16x32_bf16(af1, wf[n*4+1], acc[n], 0, 0, 0);
        acc[n] = __builtin_amdgcn_mfma_f32_16x16x32_bf16(af2, wf[n*4+2], acc[n], 0, 0, 0);
        acc[n] = __builtin_amdgcn_mfma_f32_16x16x32_bf16(af3, wf[n*4+3], acc[n], 0, 0, 0);
      }
      const bool last = (t == TT);
      #pragma unroll
      for (int jj = 0; jj < 2; ++jj) {
        float pi = jh ? acc[0][2 + jj] : acc[0][jj];
        float pf = jh ? acc[1][2 + jj] : acc[1][jj];
        float pg = jh ? acc[2][2 + jj] : acc[2][jj];
        float po = jh ? acc[3][2 + jj] : acc[3][jj];
        float iv = sigm(pi);
        float fv = sigm(pf);
        float gv = tanh_fast(pg);
        float ov = sigm(po);
        float c  = fmaf(fv, cst[jj], iv * gv);
        cst[jj] = c;
        float h  = ov * tanh_fast(c);
        const int row = q * 4 + jbase + jj;
        const int off = (2 * colw) ^ ((row & 7) << 4);
        *(unsigned short*)((char*)h1wr + row * 128 + off) = f2bf(h);
        if (last) h1f[row * HH + colw] = h;
      }
    }
    __syncthreads();   // writes(t) visible to readers(t+1); opposite buffers safe
  }

  // ---- FC epilogue: out[b][o] = h1_final[b] . Wfc[o] + bfc[o] ----
  if (tid < BB * 7) {
    const int b = tid / 7, o = tid % 7;
    float s = bfc[o];
    #pragma unroll
    for (int k = 0; k < HH; ++k) s = fmaf(h1f[b * HH + k], Wfc[o * HH + k], s);
    out[(size_t)(b0 + b) * 7 + o] = s;
  }
}

extern "C" void kernel_launch(void* const* d_in, const int* in_sizes, int n_in,
                              void* d_out, int out_size, void* d_ws, size_t ws_size,
                              hipStream_t stream) {
  const float* x    = (const float*)d_in[0];
  const float* Wih0 = (const float*)d_in[1];
  const float* Whh0 = (const float*)d_in[2];
  const float* bih0 = (const float*)d_in[3];
  const float* bhh0 = (const float*)d_in[4];
  const float* Wih1 = (const float*)d_in[5];
  const float* Whh1 = (const float*)d_in[6];
  const float* bih1 = (const float*)d_in[7];
  const float* bhh1 = (const float*)d_in[8];
  const float* Wfc  = (const float*)d_in[9];
  const float* bfc  = (const float*)d_in[10];
  float* out = (float*)d_out;

  dim3 grid(4096 / BB);   // 256 workgroups, 1 per CU
  dim3 block(1024);       // 16 waves: 8 layer-0 + 8 layer-1, row-split pairs
  hipLaunchKernelGGL(lstm2_fused, grid, block, 0, stream,
                     x, Wih0, Whh0, bih0, bhh0, Wih1, Whh1, bih1, bhh1, Wfc, bfc, out);
}

// Round 3
// 370.958 us; speedup vs baseline: 1.3498x; 1.3498x over previous
//
#include <hip/hip_runtime.h>
#include <hip/hip_bf16.h>

#define HH 64
#define TT 512
#define BB 16

typedef __attribute__((ext_vector_type(8))) short short8;
typedef __attribute__((ext_vector_type(4))) float f32x4;

static __device__ __forceinline__ unsigned short f2bf(float f) {
  unsigned u = __float_as_uint(f);
  u += 0x7fffu + ((u >> 16) & 1u);   // RNE (used for one-time weight pack only)
  return (unsigned short)(u >> 16);
}

static __device__ __forceinline__ float sigm(float x) {
  float e = __builtin_amdgcn_exp2f(-1.442695041f * x);
  return __builtin_amdgcn_rcpf(1.0f + e);
}
static __device__ __forceinline__ float tanh_fast(float x) {
  float e = __builtin_amdgcn_exp2f(2.885390082f * x);
  return 1.0f - 2.0f * __builtin_amdgcn_rcpf(1.0f + e);
}

static __device__ __forceinline__ short8 pack8(const float* __restrict__ p) {
  const float4* p4 = (const float4*)p;
  float4 a = p4[0], b = p4[1];
  short8 r;
  r[0] = (short)f2bf(a.x); r[1] = (short)f2bf(a.y);
  r[2] = (short)f2bf(a.z); r[3] = (short)f2bf(a.w);
  r[4] = (short)f2bf(b.x); r[5] = (short)f2bf(b.y);
  r[6] = (short)f2bf(b.z); r[7] = (short)f2bf(b.w);
  return r;
}

#define MF(A, B, C) __builtin_amdgcn_mfma_f32_16x16x32_bf16((A), (B), (C), 0, 0, 0)

// ---- one LSTM-layer-0 step, phase P (compile-time). Reads h0buf[P^1], writes h0buf[P].
#define STEP_A(P, XP) {                                                        \
    const char* rd = (const char*)h0buf[(P) ^ 1];                              \
    short8 af0 = *(const short8*)(rd + rdo0);                                  \
    short8 af1 = *(const short8*)(rd + rdo1);                                  \
    f32x4 xv = *(const f32x4*)(XP);                                            \
    f32x4 a0 = MF(af0, wf[0], bs[0]); a0 = MF(af1, wf[1], a0);                 \
    f32x4 a1 = MF(af0, wf[2], bs[1]); a1 = MF(af1, wf[3], a1);                 \
    f32x4 a2 = MF(af0, wf[4], bs[2]); a2 = MF(af1, wf[5], a2);                 \
    f32x4 a3 = MF(af0, wf[6], bs[3]); a3 = MF(af1, wf[7], a3);                 \
    char* wrb = (char*)h0buf[P];                                               \
    _Pragma("unroll")                                                          \
    for (int j = 0; j < 4; ++j) {                                              \
      float pi = fmaf(xv[j], wx[0], a0[j]);                                    \
      float pf = fmaf(xv[j], wx[1], a1[j]);                                    \
      float pg = fmaf(xv[j], wx[2], a2[j]);                                    \
      float po = fmaf(xv[j], wx[3], a3[j]);                                    \
      float iv = sigm(pi), fv = sigm(pf);                                      \
      float gv = tanh_fast(pg), ov = sigm(po);                                 \
      float c = fmaf(fv, cst[j], iv * gv);                                     \
      cst[j] = c;                                                              \
      float h = ov * tanh_fast(c);                                             \
      *(__hip_bfloat16*)(wrb + wro[j]) = __float2bfloat16(h);                  \
    }                                                                          \
  }

// ---- one LSTM-layer-1 step, phase P. Reads h0buf[P^1] (input) + h1buf[P]
// (recurrent, 2 steps old), writes h1buf[P^1].
#define STEP_B(P, LAST) {                                                      \
    const char* rd0 = (const char*)h0buf[(P) ^ 1];                             \
    const char* rd1 = (const char*)h1buf[P];                                   \
    short8 af0 = *(const short8*)(rd0 + rdo0);                                 \
    short8 af1 = *(const short8*)(rd0 + rdo1);                                 \
    short8 af2 = *(const short8*)(rd1 + rdo0);                                 \
    short8 af3 = *(const short8*)(rd1 + rdo1);                                 \
    f32x4 a0 = MF(af0, wf[0],  bs[0]); a0 = MF(af1, wf[1],  a0);               \
    a0 = MF(af2, wf[2],  a0);  a0 = MF(af3, wf[3],  a0);                       \
    f32x4 a1 = MF(af0, wf[4],  bs[1]); a1 = MF(af1, wf[5],  a1);               \
    a1 = MF(af2, wf[6],  a1);  a1 = MF(af3, wf[7],  a1);                       \
    f32x4 a2 = MF(af0, wf[8],  bs[2]); a2 = MF(af1, wf[9],  a2);               \
    a2 = MF(af2, wf[10], a2);  a2 = MF(af3, wf[11], a2);                       \
    f32x4 a3 = MF(af0, wf[12], bs[3]); a3 = MF(af1, wf[13], a3);               \
    a3 = MF(af2, wf[14], a3);  a3 = MF(af3, wf[15], a3);                       \
    char* wrb = (char*)h1buf[(P) ^ 1];                                         \
    _Pragma("unroll")                                                          \
    for (int j = 0; j < 4; ++j) {                                              \
      float iv = sigm(a0[j]), fv = sigm(a1[j]);                                \
      float gv = tanh_fast(a2[j]), ov = sigm(a3[j]);                           \
      float c = fmaf(fv, cst[j], iv * gv);                                     \
      cst[j] = c;                                                              \
      float h = ov * tanh_fast(c);                                             \
      *(__hip_bfloat16*)(wrb + wro[j]) = __float2bfloat16(h);                  \
      if (LAST) h1f[(q * 4 + j) * HH + colw] = h;                              \
    }                                                                          \
  }

__global__ __launch_bounds__(512, 2)
void lstm2_fused(const float* __restrict__ x,
                 const float* __restrict__ Wih0, const float* __restrict__ Whh0,
                 const float* __restrict__ bih0, const float* __restrict__ bhh0,
                 const float* __restrict__ Wih1, const float* __restrict__ Whh1,
                 const float* __restrict__ bih1, const float* __restrict__ bhh1,
                 const float* __restrict__ Wfc,  const float* __restrict__ bfc,
                 float* __restrict__ out)
{
  __shared__ float xs[TT * BB];                               // 32 KB, xs[t][row]
  __shared__ __align__(16) unsigned short h0buf[2][BB * HH];  // dbuf bf16, swizzled
  __shared__ __align__(16) unsigned short h1buf[2][BB * HH];
  __shared__ float h1f[BB * HH];                              // fp32 final h1

  const int tid  = threadIdx.x;
  const int wave = tid >> 6;
  const int lane = tid & 63;
  const int grp  = wave >> 2;      // 0: layer0 (4 waves), 1: layer1 (4 waves)
  const int w    = wave & 3;       // column-block 0..3
  const int m    = lane & 15;
  const int q    = lane >> 4;
  const int b0   = blockIdx.x * BB;

  // ---- stage x transposed: xs[t][r] = x[b0+r][t] ----
  {
    const int t = tid;             // blockDim.x == 512 == TT
    #pragma unroll
    for (int r = 0; r < BB; ++r)
      xs[t * BB + r] = x[(size_t)(b0 + r) * TT + t];
  }
  // zero h state (bf16 zero == 0x0000): each buf = 1024 uints
  ((unsigned int*)h0buf)[tid] = 0; ((unsigned int*)h0buf)[tid + 512] = 0;
  ((unsigned int*)h1buf)[tid] = 0; ((unsigned int*)h1buf)[tid + 512] = 0;

  // ---- pack weight B-fragments into registers (held across the whole loop) ----
  // wave w owns gate n-tiles {4n+w}: n=0->i,1->f,2->g,3->o, cols 16w..16w+15.
  // B-frag: lane holds Wmat[col=16*tile+m][k0+j], j=0..7, k0 = kt*32 + q*8.
  short8 wf[16];
  f32x4 bs[4];
  float wx[4];
  #pragma unroll
  for (int n = 0; n < 4; ++n) {
    const int colg = 16 * (4 * n + w) + m;
    if (grp == 0) {
      const float b = bih0[colg] + bhh0[colg];
      bs[n][0] = b; bs[n][1] = b; bs[n][2] = b; bs[n][3] = b;
      wx[n] = Wih0[colg];
      #pragma unroll
      for (int kt = 0; kt < 2; ++kt)
        wf[n * 2 + kt] = pack8(Whh0 + colg * HH + kt * 32 + q * 8);
    } else {
      const float b = bih1[colg] + bhh1[colg];
      bs[n][0] = b; bs[n][1] = b; bs[n][2] = b; bs[n][3] = b;
      wx[n] = 0.f;
      #pragma unroll
      for (int kt = 0; kt < 4; ++kt) {   // kt 0,1: Wih1 (h0 input); kt 2,3: Whh1
        const float* Wsrc = (kt < 2) ? Wih1 : Whh1;
        wf[n * 4 + kt] = pack8(Wsrc + colg * HH + (kt & 1) * 32 + q * 8);
      }
    }
  }

  // ---- loop-invariant LDS byte offsets (swizzle: 16B blocks XOR (row&7)<<4) ----
  const int colw = 16 * w + m;     // my h column within [0,64)
  const int rdo0 = m * 128 + ((q * 16) ^ ((m & 7) << 4));        // kt=0 A-frag
  const int rdo1 = m * 128 + ((64 + q * 16) ^ ((m & 7) << 4));   // kt=1 A-frag
  int wro[4];
  #pragma unroll
  for (int j = 0; j < 4; ++j) {
    const int row = q * 4 + j;
    wro[j] = row * 128 + ((2 * colw) ^ ((row & 7) << 4));
  }

  __syncthreads();   // x staged + h zeroed

  float cst[4] = {0.f, 0.f, 0.f, 0.f};
  const float* xp = xs + q * 4;    // advances 16 floats per layer-0 step

  // Iteration t (t&1 == phase P): A computes L0 step t (t<TT);
  // B computes L1 step t-1 (t>=1). ONE barrier per step.
  // t=0 peel (P=0): A only.
  if (grp == 0) { STEP_A(0, xp) }
  xp += BB;
  __syncthreads();

  #pragma unroll 1
  for (int k = 0; k < (TT - 2) / 2; ++k) {   // t = 1..510
    if (grp == 0) { STEP_A(1, xp) } else { STEP_B(1, false) }
    xp += BB;
    __syncthreads();
    if (grp == 0) { STEP_A(0, xp) } else { STEP_B(0, false) }
    xp += BB;
    __syncthreads();
  }
  // t=511 (P=1): both.
  if (grp == 0) { STEP_A(1, xp) } else { STEP_B(1, false) }
  __syncthreads();
  // t=512 (P=0): B only, final h1 also spilled to fp32.
  if (grp == 1) { STEP_B(0, true) }
  __syncthreads();

  // ---- FC epilogue: out[b][o] = h1_final[b] . Wfc[o] + bfc[o] ----
  if (tid < BB * 7) {
    const int b = tid / 7, o = tid % 7;
    float s = bfc[o];
    #pragma unroll
    for (int k = 0; k < HH; ++k) s = fmaf(h1f[b * HH + k], Wfc[o * HH + k], s);
    out[(size_t)(b0 + b) * 7 + o] = s;
  }
}

extern "C" void kernel_launch(void* const* d_in, const int* in_sizes, int n_in,
                              void* d_out, int out_size, void* d_ws, size_t ws_size,
                              hipStream_t stream) {
  const float* x    = (const float*)d_in[0];
  const float* Wih0 = (const float*)d_in[1];
  const float* Whh0 = (const float*)d_in[2];
  const float* bih0 = (const float*)d_in[3];
  const float* bhh0 = (const float*)d_in[4];
  const float* Wih1 = (const float*)d_in[5];
  const float* Whh1 = (const float*)d_in[6];
  const float* bih1 = (const float*)d_in[7];
  const float* bhh1 = (const float*)d_in[8];
  const float* Wfc  = (const float*)d_in[9];
  const float* bfc  = (const float*)d_in[10];
  float* out = (float*)d_out;

  dim3 grid(4096 / BB);   // 256 workgroups, 1 per CU
  dim3 block(512);        // 8 waves: 4 layer-0 + 4 layer-1, pipelined
  hipLaunchKernelGGL(lstm2_fused, grid, block, 0, stream,
                     x, Wih0, Whh0, bih0, bhh0, Wih1, Whh1, bih1, bhh1, Wfc, bfc, out);
}